// Round 1
// baseline (637.497 us; speedup 1.0000x reference)
//
#include <hip/hip_runtime.h>

#define PI_F 3.141592653f
#define NB 1024
#define IOU_THR_F 0.1f

__device__ __forceinline__ float limit_period_f(float v) {
    return v - floorf(v / (2.0f * PI_F) + 0.5f) * (2.0f * PI_F);
}

// ---------------------------------------------------------------------------
// K1: per-pair rotated BEV IoU -> packed bitmask (iou > 0.1)
// grid (4, 1024) x 256 threads; row i = blockIdx.y, col j = blockIdx.x*256+tid
// Polygon verts live in LDS (ping-pong) to avoid scratch from dynamic indexing.
// ---------------------------------------------------------------------------
__global__ __launch_bounds__(256) void iou_mask_kernel(
    const float* __restrict__ boxes,
    unsigned long long* __restrict__ maskrow)
{
    __shared__ float vxs[2][8][256];
    __shared__ float vys[2][8][256];
    const int tid = threadIdx.x;
    const int i = blockIdx.y;
    const int j = blockIdx.x * 256 + tid;

    const float ax = boxes[i*7+0], ay = boxes[i*7+1], az = boxes[i*7+2];
    const float adx = boxes[i*7+3], ady = boxes[i*7+4], adz = boxes[i*7+5];
    const float aang = limit_period_f(boxes[i*7+6]);
    const float bx = boxes[j*7+0], by = boxes[j*7+1], bz = boxes[j*7+2];
    const float bdx = boxes[j*7+3], bdy = boxes[j*7+4], bdz = boxes[j*7+5];
    const float bang = limit_period_f(boxes[j*7+6]);

    float ca, sa, cb, sb;
    sincosf(aang, &sa, &ca);
    sincosf(bang, &sb, &cb);

    // A corners -> LDS buffer 0   (local = [[.5,.5],[-.5,.5],[-.5,-.5],[.5,-.5]]*(dx,dy))
    {
        const float hx = 0.5f*adx, hy = 0.5f*ady;
        const float lxs[4] = { hx, -hx, -hx, hx };
        const float lys[4] = { hy, hy, -hy, -hy };
        #pragma unroll
        for (int k = 0; k < 4; ++k) {
            vxs[0][k][tid] = lxs[k]*ca - lys[k]*sa + ax;
            vys[0][k][tid] = lxs[k]*sa + lys[k]*ca + ay;
        }
    }
    // B corners in registers
    float pbx[4], pby[4];
    {
        const float hx = 0.5f*bdx, hy = 0.5f*bdy;
        const float lxs[4] = { hx, -hx, -hx, hx };
        const float lys[4] = { hy, hy, -hy, -hy };
        #pragma unroll
        for (int k = 0; k < 4; ++k) {
            pbx[k] = lxs[k]*cb - lys[k]*sb + bx;
            pby[k] = lxs[k]*sb + lys[k]*cb + by;
        }
    }

    int n = 4;
    int cur = 0;
    #pragma unroll
    for (int e = 0; e < 4; ++e) {
        const float eax = pbx[e], eay = pby[e];
        const float ebx2 = pbx[(e+1)&3], eby2 = pby[(e+1)&3];
        const float dx = ebx2 - eax, dy = eby2 - eay;
        int m = 0;
        if (n > 0) {
            int pidx = n - 1; if (pidx > 7) pidx = 7;
            float px = vxs[cur][pidx][tid];
            float py = vys[cur][pidx][tid];
            float sq = dx*(py - eay) - dy*(px - eax);
            #pragma unroll
            for (int k = 0; k < 8; ++k) {
                if (k < n) {
                    const float cx = vxs[cur][k][tid];
                    const float cy = vys[cur][k][tid];
                    const float sp = dx*(cy - eay) - dy*(cx - eax);
                    const bool in_p = (sp >= 0.0f);
                    const bool in_q = (sq >= 0.0f);
                    if (in_p != in_q) {
                        float den = sq - sp;
                        den = (fabsf(den) < 1e-9f) ? 1e-9f : den;  // ref: always +1e-9
                        const float t = sq / den;
                        if (m < 8) {
                            vxs[cur^1][m][tid] = px + t*(cx - px);
                            vys[cur^1][m][tid] = py + t*(cy - py);
                        }
                        ++m;
                    }
                    if (in_p) {
                        if (m < 8) {
                            vxs[cur^1][m][tid] = cx;
                            vys[cur^1][m][tid] = cy;
                        }
                        ++m;
                    }
                    px = cx; py = cy; sq = sp;
                }
            }
        }
        n = m;
        cur ^= 1;
    }

    float area = 0.0f;
    if (n >= 3) {
        float s = 0.0f;
        const float x0 = vxs[cur][0][tid];
        const float y0 = vys[cur][0][tid];
        #pragma unroll
        for (int k = 0; k < 8; ++k) {
            if (k < n) {
                float nx, ny;
                if (k == n - 1) { nx = x0; ny = y0; }
                else {
                    int nk = k + 1; if (nk > 7) nk = 7;
                    nx = vxs[cur][nk][tid]; ny = vys[cur][nk][tid];
                }
                s += vxs[cur][k][tid]*ny - vys[cur][k][tid]*nx;
            }
        }
        area = 0.5f * fabsf(s);
    }

    const float zh = fminf(az + adz*0.5f, bz + bdz*0.5f);
    const float zl = fmaxf(az - adz*0.5f, bz - bdz*0.5f);
    const float h = fmaxf(zh - zl, 0.0f);
    const float inter = area * h;
    const float va = adx*ady*adz;
    const float vb = bdx*bdy*bdz;
    const float iou = inter / fmaxf(va + vb - inter, 1e-6f);

    const unsigned long long bal = __ballot(iou > IOU_THR_F);
    if ((tid & 63) == 0) {
        maskrow[(size_t)i*16 + (size_t)(j >> 6)] = bal;
    }
}

// ---------------------------------------------------------------------------
// K2: sequential clustering. 1 block x 64 threads (1 wave).
// Per-lane: ci for boxes lane*16..lane*16+15 (ushort[16], fully unrolled),
// zmask bit k == (ci==0). Min-index reduce via shfl_xor; mask row from L2.
// ---------------------------------------------------------------------------
__global__ __launch_bounds__(64) void cluster_kernel(
    const unsigned long long* __restrict__ maskrow,
    int* __restrict__ ci_out)
{
    const int lane = threadIdx.x;
    unsigned short ci[16];
    #pragma unroll
    for (int k = 0; k < 16; ++k) ci[k] = 0;
    unsigned int zmask = 0xFFFFu;
    int cid = 0;

    for (int it = 0; it < NB; ++it) {
        int myidx = zmask ? (lane * 16 + (__ffs(zmask) - 1)) : (1 << 30);
        int best = myidx;
        #pragma unroll
        for (int off = 32; off >= 1; off >>= 1) {
            int o = __shfl_xor(best, off);
            best = min(best, o);
        }
        if (best >= (1 << 30)) break;   // no zeros left: all later iters are no-ops
        ++cid;
        // mask bits for my 16 boxes: word best*16 + lane/4, 16-bit slice (lane&3)
        const unsigned long long w = maskrow[(size_t)best * 16 + (size_t)(lane >> 2)];
        const unsigned int bits = (unsigned int)((w >> ((lane & 3) * 16)) & 0xFFFFu);
        if (bits) {
            #pragma unroll
            for (int k = 0; k < 16; ++k)
                if (bits & (1u << k)) ci[k] = (unsigned short)cid;  // reassign allowed
            zmask &= ~bits;
        }
    }

    #pragma unroll
    for (int k = 0; k < 16; ++k) ci_out[lane * 16 + k] = (int)ci[k];
}

// ---------------------------------------------------------------------------
// K3: per-cluster fusion. 1024 blocks x 64 threads (1 wave). Block b fuses
// cluster id b+1. Deterministic member gather via lane prefix sum.
// ---------------------------------------------------------------------------
__global__ __launch_bounds__(64) void fuse_kernel(
    const float* __restrict__ boxes,
    const float* __restrict__ scores,
    const int* __restrict__ ci,
    float* __restrict__ out)
{
    __shared__ float ms[NB];
    __shared__ int   mi[NB];

    const int b = blockIdx.x;
    const int lane = threadIdx.x;
    const int target = b + 1;

    unsigned int mymask = 0;
    #pragma unroll
    for (int k = 0; k < 16; ++k) {
        const int idx = lane * 16 + k;
        if (ci[idx] == target) mymask |= (1u << k);
    }
    const bool anyv = (__ballot(mymask != 0) != 0ULL);

    float* outb = out + (size_t)b * 7;
    float* outs = out + 7 * NB;
    float* outv = out + 8 * NB;

    if (!anyv) {
        if (lane == 0) {
            #pragma unroll
            for (int c = 0; c < 7; ++c) outb[c] = 0.0f;
            outs[b] = 0.0f;
            outv[b] = 0.0f;
        }
        return;
    }

    // pass 1: ssum + argmax (first index of max)
    float ssum = 0.0f, smax = -1.0f;
    int sidx = 1 << 30;
    #pragma unroll
    for (int k = 0; k < 16; ++k) {
        if (mymask & (1u << k)) {
            const int idx = lane * 16 + k;
            const float s = scores[idx];
            ssum += s;
            if (s > smax || (s == smax && idx < sidx)) { smax = s; sidx = idx; }
        }
    }
    #pragma unroll
    for (int off = 32; off >= 1; off >>= 1) {
        ssum += __shfl_xor(ssum, off);
        const float om = __shfl_xor(smax, off);
        const int   oi = __shfl_xor(sidx, off);
        if (om > smax || (om == smax && oi < sidx)) { smax = om; sidx = oi; }
    }
    const float ref = limit_period_f(boxes[sidx * 7 + 6]);

    // pass 2: sc_gt
    float sc_gt = 0.0f;
    #pragma unroll
    for (int k = 0; k < 16; ++k) {
        if (mymask & (1u << k)) {
            const int idx = lane * 16 + k;
            const float dir = limit_period_f(boxes[idx * 7 + 6]);
            float diff = fabsf(dir - ref);
            if (diff > PI_F) diff = 2.0f * PI_F - diff;
            if (diff > PI_F * 0.5f) sc_gt += scores[idx];
        }
    }
    #pragma unroll
    for (int off = 32; off >= 1; off >>= 1) sc_gt += __shfl_xor(sc_gt, off);
    const bool flip_gt = (sc_gt <= (ssum - sc_gt));

    // pass 3: weighted sums (6 center comps + sin + cos)
    float acc[6] = {0,0,0,0,0,0};
    float ssin = 0.0f, scos = 0.0f;
    #pragma unroll
    for (int k = 0; k < 16; ++k) {
        if (mymask & (1u << k)) {
            const int idx = lane * 16 + k;
            const float s = scores[idx];
            const float w = s / ssum;   // valid => ssum > 0
            const float dir = limit_period_f(boxes[idx * 7 + 6]);
            float diff = fabsf(dir - ref);
            if (diff > PI_F) diff = 2.0f * PI_F - diff;
            const bool gt = (diff > PI_F * 0.5f);
            const bool add = flip_gt ? gt : (!gt);
            const float d2 = limit_period_f(dir + (add ? PI_F : 0.0f));
            float sd, cd;
            sincosf(d2, &sd, &cd);
            ssin += sd * w;
            scos += cd * w;
            #pragma unroll
            for (int c = 0; c < 6; ++c) acc[c] += boxes[idx * 7 + c] * w;
        }
    }
    #pragma unroll
    for (int off = 32; off >= 1; off >>= 1) {
        ssin += __shfl_xor(ssin, off);
        scos += __shfl_xor(scos, off);
        #pragma unroll
        for (int c = 0; c < 6; ++c) acc[c] += __shfl_xor(acc[c], off);
    }
    const float theta = atan2f(ssin, scos);

    // pass 4: score fusion  s_f = min(sum_r s_sorted[r]^(r+1), 1)
    // rank = #(members with larger score) + #(equal score, smaller idx);
    // tie exponents give identical sums regardless of sort tie order.
    const int cnt = __popc(mymask);
    int x = cnt;
    #pragma unroll
    for (int off = 1; off < 64; off <<= 1) {
        const int y = __shfl_up(x, off);
        if (lane >= off) x += y;
    }
    const int base = x - cnt;
    const int K = __shfl(x, 63);
    {
        int p = base;
        #pragma unroll
        for (int k = 0; k < 16; ++k) {
            if (mymask & (1u << k)) {
                const int idx = lane * 16 + k;
                ms[p] = scores[idx];
                mi[p] = idx;
                ++p;
            }
        }
    }
    __syncthreads();

    float sf = 0.0f;
    for (int e = lane; e < K; e += 64) {
        const float v = ms[e];
        const int ix = mi[e];
        int rank = 0;
        for (int t = 0; t < K; ++t) {
            const float u = ms[t];
            if (u > v || (u == v && mi[t] < ix)) ++rank;
        }
        sf += powf(v, (float)(rank + 1));
    }
    #pragma unroll
    for (int off = 32; off >= 1; off >>= 1) sf += __shfl_xor(sf, off);
    sf = fminf(sf, 1.0f);

    if (lane == 0) {
        #pragma unroll
        for (int c = 0; c < 6; ++c) outb[c] = acc[c];
        outb[6] = theta;
        outs[b] = sf;
        outv[b] = 1.0f;
    }
}

// ---------------------------------------------------------------------------
extern "C" void kernel_launch(void* const* d_in, const int* in_sizes, int n_in,
                              void* d_out, int out_size, void* d_ws, size_t ws_size,
                              hipStream_t stream) {
    const float* boxes  = (const float*)d_in[0];   // (1024,7) f32
    const float* scores = (const float*)d_in[1];   // (1024,)  f32
    float* out = (float*)d_out;                    // 7*1024 + 1024 + 1024

    unsigned long long* maskrow = (unsigned long long*)d_ws;          // 1024*16 u64 = 128 KB
    int* ci = (int*)((char*)d_ws + (size_t)NB * 16 * sizeof(unsigned long long)); // 4 KB

    dim3 g1(4, NB, 1);
    iou_mask_kernel<<<g1, 256, 0, stream>>>(boxes, maskrow);
    cluster_kernel<<<1, 64, 0, stream>>>(maskrow, ci);
    fuse_kernel<<<NB, 64, 0, stream>>>(boxes, scores, ci, out);
}

// Round 2
// 131.586 us; speedup vs baseline: 4.8447x; 4.8447x over previous
//
#include <hip/hip_runtime.h>

#define PI_F 3.141592653f
#define NB 1024
#define NW 16            // 16 x u64 words per 1024-bit row
#define IOU_THR_F 0.1f

__device__ __forceinline__ float limit_period_f(float v) {
    return v - floorf(v / (2.0f * PI_F) + 0.5f) * (2.0f * PI_F);
}

// swizzled word index: word w of row r lives at r*16 + (w ^ (r&15))
// -> spreads the stride-128B column accesses across LDS banks
__device__ __forceinline__ int widx(int r, int w) {
    return (r << 4) | (w ^ (r & 15));
}

// ---------------------------------------------------------------------------
// K1: per-pair rotated BEV IoU -> packed bitmask (iou > 0.1)
// grid (4, 1024) x 256 threads; row i = blockIdx.y, col j = blockIdx.x*256+tid
// ---------------------------------------------------------------------------
__global__ __launch_bounds__(256) void iou_mask_kernel(
    const float* __restrict__ boxes,
    unsigned long long* __restrict__ maskrow)
{
    __shared__ float vxs[2][8][256];
    __shared__ float vys[2][8][256];
    const int tid = threadIdx.x;
    const int i = blockIdx.y;
    const int j = blockIdx.x * 256 + tid;

    const float ax = boxes[i*7+0], ay = boxes[i*7+1], az = boxes[i*7+2];
    const float adx = boxes[i*7+3], ady = boxes[i*7+4], adz = boxes[i*7+5];
    const float aang = limit_period_f(boxes[i*7+6]);
    const float bx = boxes[j*7+0], by = boxes[j*7+1], bz = boxes[j*7+2];
    const float bdx = boxes[j*7+3], bdy = boxes[j*7+4], bdz = boxes[j*7+5];
    const float bang = limit_period_f(boxes[j*7+6]);

    float ca, sa, cb, sb;
    sincosf(aang, &sa, &ca);
    sincosf(bang, &sb, &cb);

    {
        const float hx = 0.5f*adx, hy = 0.5f*ady;
        const float lxs[4] = { hx, -hx, -hx, hx };
        const float lys[4] = { hy, hy, -hy, -hy };
        #pragma unroll
        for (int k = 0; k < 4; ++k) {
            vxs[0][k][tid] = lxs[k]*ca - lys[k]*sa + ax;
            vys[0][k][tid] = lxs[k]*sa + lys[k]*ca + ay;
        }
    }
    float pbx[4], pby[4];
    {
        const float hx = 0.5f*bdx, hy = 0.5f*bdy;
        const float lxs[4] = { hx, -hx, -hx, hx };
        const float lys[4] = { hy, hy, -hy, -hy };
        #pragma unroll
        for (int k = 0; k < 4; ++k) {
            pbx[k] = lxs[k]*cb - lys[k]*sb + bx;
            pby[k] = lxs[k]*sb + lys[k]*cb + by;
        }
    }

    int n = 4;
    int cur = 0;
    #pragma unroll
    for (int e = 0; e < 4; ++e) {
        const float eax = pbx[e], eay = pby[e];
        const float ebx2 = pbx[(e+1)&3], eby2 = pby[(e+1)&3];
        const float dx = ebx2 - eax, dy = eby2 - eay;
        int m = 0;
        if (n > 0) {
            int pidx = n - 1; if (pidx > 7) pidx = 7;
            float px = vxs[cur][pidx][tid];
            float py = vys[cur][pidx][tid];
            float sq = dx*(py - eay) - dy*(px - eax);
            #pragma unroll
            for (int k = 0; k < 8; ++k) {
                if (k < n) {
                    const float cx = vxs[cur][k][tid];
                    const float cy = vys[cur][k][tid];
                    const float sp = dx*(cy - eay) - dy*(cx - eax);
                    const bool in_p = (sp >= 0.0f);
                    const bool in_q = (sq >= 0.0f);
                    if (in_p != in_q) {
                        float den = sq - sp;
                        den = (fabsf(den) < 1e-9f) ? 1e-9f : den;  // ref semantics
                        const float t = sq / den;
                        if (m < 8) {
                            vxs[cur^1][m][tid] = px + t*(cx - px);
                            vys[cur^1][m][tid] = py + t*(cy - py);
                        }
                        ++m;
                    }
                    if (in_p) {
                        if (m < 8) {
                            vxs[cur^1][m][tid] = cx;
                            vys[cur^1][m][tid] = cy;
                        }
                        ++m;
                    }
                    px = cx; py = cy; sq = sp;
                }
            }
        }
        n = m;
        cur ^= 1;
    }

    float area = 0.0f;
    if (n >= 3) {
        float s = 0.0f;
        const float x0 = vxs[cur][0][tid];
        const float y0 = vys[cur][0][tid];
        #pragma unroll
        for (int k = 0; k < 8; ++k) {
            if (k < n) {
                float nx, ny;
                if (k == n - 1) { nx = x0; ny = y0; }
                else {
                    int nk = k + 1; if (nk > 7) nk = 7;
                    nx = vxs[cur][nk][tid]; ny = vys[cur][nk][tid];
                }
                s += vxs[cur][k][tid]*ny - vys[cur][k][tid]*nx;
            }
        }
        area = 0.5f * fabsf(s);
    }

    const float zh = fminf(az + adz*0.5f, bz + bdz*0.5f);
    const float zl = fmaxf(az - adz*0.5f, bz - bdz*0.5f);
    const float h = fmaxf(zh - zl, 0.0f);
    const float inter = area * h;
    const float va = adx*ady*adz;
    const float vb = bdx*bdy*bdz;
    const float iou = inter / fmaxf(va + vb - inter, 1e-6f);

    const unsigned long long bal = __ballot(iou > IOU_THR_F);
    if ((tid & 63) == 0) {
        maskrow[(size_t)i*NW + (size_t)(j >> 6)] = bal;
    }
}

// ---------------------------------------------------------------------------
// K2: clustering, bit-parallel chunked formulation. 1 block x 256 threads.
//
// Semantics: seeds are picked in increasing index order among boxes still
// unlabeled; a seed labels (overwrites) every box its IoU-row covers.
// Final label of box j = rank of LAST seed whose row contains j.
//
// Phase A: stage full 1024x1024 bit matrix in LDS (swizzled), init ci.
// Phase B (wave 0): 16 chunks of 64. "Safe" boxes (empty row AND column in
//   the 64x64 diagonal block, besides self) are seeds iff eligible - O(1)
//   via ballot; the rest go through a short serial shfl loop. Future
//   eligibility words cleared with a 64-lane OR butterfly.
// Phase C: each seed row scatters its rank via LDS atomicMax.
// ---------------------------------------------------------------------------
__global__ __launch_bounds__(256) void cluster_kernel(
    const unsigned long long* __restrict__ maskrow,
    int* __restrict__ ci_out)
{
    extern __shared__ char smem[];
    unsigned long long* mat = (unsigned long long*)smem;                  // 1024*16 u64 = 128 KB
    int* ci_lds = (int*)(smem + 131072);                                  // 1024 int = 4 KB
    unsigned long long* seedmask = (unsigned long long*)(smem + 135168);  // 16 u64
    int* rankbase = (int*)(smem + 135296);                                // 16 int

    const int tid = threadIdx.x;

    // ---- phase A ----
    for (int i = tid; i < NB; i += 256) ci_lds[i] = 0;
    #pragma unroll 4
    for (int i = 0; i < 64; ++i) {
        const int idx = tid + i * 256;          // coalesced across threads
        const int r = idx >> 4, w = idx & 15;
        mat[widx(r, w)] = maskrow[idx];
    }
    __syncthreads();

    // ---- phase B: wave 0 only ----
    if (tid < 64) {
        unsigned long long zm[NW];
        #pragma unroll
        for (int w = 0; w < NW; ++w) zm[w] = ~0ull;
        int base = 0;

        #pragma unroll
        for (int c = 0; c < NW; ++c) {
            const unsigned long long selfbit = 1ull << tid;
            const unsigned long long D = mat[widx(c * 64 + tid, c)];  // diag-block row
            // column-occupancy of the diag block (off-diagonal bits of any row)
            unsigned long long U = D & ~selfbit;
            #pragma unroll
            for (int off = 1; off < 64; off <<= 1)
                U |= __shfl_xor(U, off);
            // safe = empty row AND empty column (off-diagonal) in diag block
            const unsigned long long A = __ballot(D == selfbit) & ~U;

            unsigned long long E = zm[c];       // eligibility at chunk start
            unsigned long long S = E & A;       // safe seeds: order-independent
            unsigned long long rem = E & ~A;    // non-safe eligible: serial
            while (rem) {
                const int t = __ffsll(rem) - 1;
                rem &= rem - 1;
                if ((E >> t) & 1ull) {
                    S |= 1ull << t;
                    const unsigned long long Dt = __shfl(D, t);
                    E &= ~Dt;                   // cannot touch safe bits (col empty)
                    rem &= E;
                }
            }

            if (tid == 0) { seedmask[c] = S; rankbase[c] = base; }
            base += (int)__popcll(S);

            // batch-clear future eligibility words with this chunk's seed rows
            const unsigned long long am = ((S >> tid) & 1ull) ? ~0ull : 0ull;
            #pragma unroll
            for (int w = c + 1; w < NW; ++w) {
                unsigned long long v = mat[widx(c * 64 + tid, w)] & am;
                if (__ballot(v != 0ull)) {
                    #pragma unroll
                    for (int off = 1; off < 64; off <<= 1)
                        v |= __shfl_xor(v, off);
                    zm[w] &= ~v;
                }
            }
        }
    }
    __syncthreads();

    // ---- phase C: label = max rank over covering seed rows ----
    for (int r = tid; r < NB; r += 256) {
        const unsigned long long S = seedmask[r >> 6];
        const int pos = r & 63;
        if ((S >> pos) & 1ull) {
            const int rank = rankbase[r >> 6]
                           + (int)__popcll(S & ((1ull << pos) - 1ull)) + 1;
            #pragma unroll
            for (int w = 0; w < NW; ++w) {
                unsigned long long bits = mat[widx(r, w)];
                while (bits) {
                    const int j = __ffsll(bits) - 1;
                    bits &= bits - 1;
                    atomicMax(&ci_lds[(w << 6) + j], rank);
                }
            }
        }
    }
    __syncthreads();
    for (int i = tid; i < NB; i += 256) ci_out[i] = ci_lds[i];
}

// ---------------------------------------------------------------------------
// K3: per-cluster fusion. 1024 blocks x 64 threads (1 wave).
// ---------------------------------------------------------------------------
__global__ __launch_bounds__(64) void fuse_kernel(
    const float* __restrict__ boxes,
    const float* __restrict__ scores,
    const int* __restrict__ ci,
    float* __restrict__ out)
{
    __shared__ float ms[NB];
    __shared__ int   mi[NB];

    const int b = blockIdx.x;
    const int lane = threadIdx.x;
    const int target = b + 1;

    unsigned int mymask = 0;
    #pragma unroll
    for (int k = 0; k < 16; ++k) {
        const int idx = lane * 16 + k;
        if (ci[idx] == target) mymask |= (1u << k);
    }
    const bool anyv = (__ballot(mymask != 0) != 0ULL);

    float* outb = out + (size_t)b * 7;
    float* outs = out + 7 * NB;
    float* outv = out + 8 * NB;

    if (!anyv) {
        if (lane == 0) {
            #pragma unroll
            for (int c = 0; c < 7; ++c) outb[c] = 0.0f;
            outs[b] = 0.0f;
            outv[b] = 0.0f;
        }
        return;
    }

    // pass 1: ssum + argmax (first index of max)
    float ssum = 0.0f, smax = -1.0f;
    int sidx = 1 << 30;
    #pragma unroll
    for (int k = 0; k < 16; ++k) {
        if (mymask & (1u << k)) {
            const int idx = lane * 16 + k;
            const float s = scores[idx];
            ssum += s;
            if (s > smax || (s == smax && idx < sidx)) { smax = s; sidx = idx; }
        }
    }
    #pragma unroll
    for (int off = 32; off >= 1; off >>= 1) {
        ssum += __shfl_xor(ssum, off);
        const float om = __shfl_xor(smax, off);
        const int   oi = __shfl_xor(sidx, off);
        if (om > smax || (om == smax && oi < sidx)) { smax = om; sidx = oi; }
    }
    const float ref = limit_period_f(boxes[sidx * 7 + 6]);

    // pass 2: sc_gt
    float sc_gt = 0.0f;
    #pragma unroll
    for (int k = 0; k < 16; ++k) {
        if (mymask & (1u << k)) {
            const int idx = lane * 16 + k;
            const float dir = limit_period_f(boxes[idx * 7 + 6]);
            float diff = fabsf(dir - ref);
            if (diff > PI_F) diff = 2.0f * PI_F - diff;
            if (diff > PI_F * 0.5f) sc_gt += scores[idx];
        }
    }
    #pragma unroll
    for (int off = 32; off >= 1; off >>= 1) sc_gt += __shfl_xor(sc_gt, off);
    const bool flip_gt = (sc_gt <= (ssum - sc_gt));

    // pass 3: weighted sums (6 center comps + sin + cos)
    float acc[6] = {0,0,0,0,0,0};
    float ssin = 0.0f, scos = 0.0f;
    #pragma unroll
    for (int k = 0; k < 16; ++k) {
        if (mymask & (1u << k)) {
            const int idx = lane * 16 + k;
            const float s = scores[idx];
            const float w = s / ssum;
            const float dir = limit_period_f(boxes[idx * 7 + 6]);
            float diff = fabsf(dir - ref);
            if (diff > PI_F) diff = 2.0f * PI_F - diff;
            const bool gt = (diff > PI_F * 0.5f);
            const bool add = flip_gt ? gt : (!gt);
            const float d2 = limit_period_f(dir + (add ? PI_F : 0.0f));
            float sd, cd;
            sincosf(d2, &sd, &cd);
            ssin += sd * w;
            scos += cd * w;
            #pragma unroll
            for (int c = 0; c < 6; ++c) acc[c] += boxes[idx * 7 + c] * w;
        }
    }
    #pragma unroll
    for (int off = 32; off >= 1; off >>= 1) {
        ssin += __shfl_xor(ssin, off);
        scos += __shfl_xor(scos, off);
        #pragma unroll
        for (int c = 0; c < 6; ++c) acc[c] += __shfl_xor(acc[c], off);
    }
    const float theta = atan2f(ssin, scos);

    // pass 4: score fusion via tie-broken ranks (matches sorted-power sum)
    const int cnt = __popc(mymask);
    int x = cnt;
    #pragma unroll
    for (int off = 1; off < 64; off <<= 1) {
        const int y = __shfl_up(x, off);
        if (lane >= off) x += y;
    }
    const int base = x - cnt;
    const int K = __shfl(x, 63);
    {
        int p = base;
        #pragma unroll
        for (int k = 0; k < 16; ++k) {
            if (mymask & (1u << k)) {
                const int idx = lane * 16 + k;
                ms[p] = scores[idx];
                mi[p] = idx;
                ++p;
            }
        }
    }
    __syncthreads();

    float sf = 0.0f;
    for (int e = lane; e < K; e += 64) {
        const float v = ms[e];
        const int ix = mi[e];
        int rank = 0;
        for (int t = 0; t < K; ++t) {
            const float u = ms[t];
            if (u > v || (u == v && mi[t] < ix)) ++rank;
        }
        sf += powf(v, (float)(rank + 1));
    }
    #pragma unroll
    for (int off = 32; off >= 1; off >>= 1) sf += __shfl_xor(sf, off);
    sf = fminf(sf, 1.0f);

    if (lane == 0) {
        #pragma unroll
        for (int c = 0; c < 6; ++c) outb[c] = acc[c];
        outb[6] = theta;
        outs[b] = sf;
        outv[b] = 1.0f;
    }
}

// ---------------------------------------------------------------------------
extern "C" void kernel_launch(void* const* d_in, const int* in_sizes, int n_in,
                              void* d_out, int out_size, void* d_ws, size_t ws_size,
                              hipStream_t stream) {
    const float* boxes  = (const float*)d_in[0];   // (1024,7) f32
    const float* scores = (const float*)d_in[1];   // (1024,)  f32
    float* out = (float*)d_out;                    // 7*1024 + 1024 + 1024

    unsigned long long* maskrow = (unsigned long long*)d_ws;          // 1024*16 u64 = 128 KB
    int* ci = (int*)((char*)d_ws + (size_t)NB * NW * sizeof(unsigned long long)); // 4 KB

    dim3 g1(4, NB, 1);
    iou_mask_kernel<<<g1, 256, 0, stream>>>(boxes, maskrow);

    const size_t SMEM = 135424;  // 128K matrix + 4K ci + seedmask/rankbase
    (void)hipFuncSetAttribute((const void*)cluster_kernel,
                              hipFuncAttributeMaxDynamicSharedMemorySize, (int)SMEM);
    cluster_kernel<<<1, 256, SMEM, stream>>>(maskrow, ci);

    fuse_kernel<<<NB, 64, 0, stream>>>(boxes, scores, ci, out);
}